// Round 17
// baseline (720.503 us; speedup 1.0000x reference)
//
#include <hip/hip_runtime.h>
#include <math.h>

#define NKER 125
#define CAP 64

struct Ptr6i { const int* p[6]; };
struct Ptr6f { const float* p[6]; };

// ---------------- fill_all: ONE pass; r = atomicAdd(cnt[dst]); recS[dst*CAP+r] = packed rec ----------------
__global__ __launch_bounds__(256) void fill_all_kernel(
    Ptr6i eis, Ptr6f eas, int* __restrict__ cnt, float4* __restrict__ recS) {
  static const int EB[7] = {0, 1250, 1563, 1643, 1663, 1668, 1670};
  static const int Es[6] = {320000, 80000, 20480, 5120, 1280, 512};
  static const int hOff[6] = {0, 20000, 25000, 26280, 26600, 26680};
  int b = blockIdx.x;
  int l = 0;
  while (b >= EB[l + 1]) l++;
  int e = (b - EB[l]) * 256 + threadIdx.x;
  if (e >= Es[l]) return;
  const int* ei = eis.p[l];
  const float* ea = eas.p[l];
  int src = ei[e];
  int dst = ei[Es[l] + e];
  int kpk = 0;
  float f[3];
#pragma unroll
  for (int d = 0; d < 3; d++) {
    float p = ea[e * 3 + d] * 4.0f;
    float kf = fminf(fmaxf(floorf(p), 0.0f), 3.0f);
    f[d] = p - kf;
    kpk |= ((int)kf) << (4 * d);
  }
  int node = hOff[l] + dst;
  int r = atomicAdd(&cnt[node], 1);
  if (r < CAP)
    recS[(size_t)node * CAP + r] =
        make_float4(__uint_as_float((unsigned)src | ((unsigned)kpk << 15)), f[0], f[1], f[2]);
}

// ---------------- conv0: L0 fully fused (direct conv + epilogue), W in LDS ----------------
// Cin=2, Cout=16, W0 = 125x2x16; LDS rows padded to 33 floats to avoid bank conflicts.
__global__ __launch_bounds__(128) void conv0_kernel(
    const int* __restrict__ cnt, const float4* __restrict__ rc,
    const float* __restrict__ x, const float* __restrict__ W,
    const float* __restrict__ R, const float* __restrict__ bias,
    float* __restrict__ h, int N) {
  __shared__ float Wl[125 * 33 + 48];   // [k*33 + ci*16 + o]; R at 4125; b at 4157
  int tid = threadIdx.x;
  for (int t = tid; t < 4000; t += 128) {
    int k = t >> 5, rem = t & 31;
    Wl[k * 33 + rem] = W[t];
  }
  if (tid < 32) Wl[4125 + tid] = R[tid];
  if (tid < 16) Wl[4157 + tid] = bias[tid];
  __syncthreads();
  int n = blockIdx.x * 128 + tid;
  if (n >= N) return;
  int deg = cnt[n];
  int m = min(deg, CAP);
  const float4* re = rc + (size_t)n * CAP;
  float acc[16];
#pragma unroll
  for (int o = 0; o < 16; o++) acc[o] = 0.0f;
  for (int i = 0; i < m; i++) {
    float4 rec = re[i];
    unsigned v = __float_as_uint(rec.x);
    int src = v & 0x7fff;
    int kpk = v >> 15;
    float f0 = rec.y, f1 = rec.z, f2 = rec.w;
    float x0 = x[(size_t)src * 2], x1 = x[(size_t)src * 2 + 1];
    float g0 = 1.0f - f0, g1 = 1.0f - f1, g2 = 1.0f - f2;
    int kb = (kpk & 15) + 5 * ((kpk >> 4) & 15) + 25 * ((kpk >> 8) & 15);
#pragma unroll
    for (int c = 0; c < 8; c++) {
      int b0 = c & 1, b1 = (c >> 1) & 1, b2 = c >> 2;
      float wp = (b0 ? f0 : g0) * (b1 ? f1 : g1) * (b2 ? f2 : g2);
      int kidx = kb + b0 + 5 * b1 + 25 * b2;
      const float* Wb = &Wl[kidx * 33];
      float wx0 = wp * x0, wx1 = wp * x1;
#pragma unroll
      for (int o = 0; o < 16; o++)
        acc[o] = fmaf(wx0, Wb[o], fmaf(wx1, Wb[16 + o], acc[o]));
    }
  }
  float invd = 1.0f / (float)max(deg, 1);
  float xa = x[(size_t)n * 2], xb = x[(size_t)n * 2 + 1];
  float* hp = h + (size_t)n * 16;
#pragma unroll
  for (int o = 0; o < 16; o++) {
    float r = Wl[4157 + o] + xa * Wl[4125 + o] + xb * Wl[4125 + 16 + o];
    float vv = fmaf(acc[o], invd, r);
    hp[o] = vv > 0.0f ? vv : expm1f(vv);
  }
}

// ---------------- build4 generic: thread owns (node, ci); plain LDS RMW; bucketed recS ----------------
template <int CINSH, int G, int KDIM, int KSG, int NT>
__global__ __launch_bounds__(NT) void build4_kernel(
    const int* __restrict__ cntL, const float4* __restrict__ rc,
    const float* __restrict__ x, float* __restrict__ A) {
  __shared__ float rows[G * KDIM];
  const int Cin = 1 << CINSH;
  int tid = threadIdx.x;
  int n0 = blockIdx.x * G;
  for (int t = tid; t < G * KDIM / 4; t += NT)
    ((float4*)rows)[t] = make_float4(0.0f, 0.0f, 0.0f, 0.0f);
  __syncthreads();
  int nl = tid >> CINSH;
  int ci = tid & (Cin - 1);
  int n = n0 + nl;
  int m = min(cntL[n], CAP);
  const float4* re = rc + (size_t)n * CAP;
  float* row = rows + nl * KDIM + ci;
  for (int i = 0; i < m; i++) {
    float4 rec = re[i];
    unsigned v = __float_as_uint(rec.x);
    int src = v & 0x7fff;
    int kpk = v >> 15;
    float f0 = rec.y, f1 = rec.z, f2 = rec.w;
    float xv = x[((size_t)src << CINSH) + ci];
    float g0 = 1.0f - f0, g1 = 1.0f - f1, g2 = 1.0f - f2;
    int kb = (kpk & 15) + 5 * ((kpk >> 4) & 15) + 25 * ((kpk >> 8) & 15);
    float* rb = row + (kb << CINSH);
    rb[0]              += (g0 * g1 * g2) * xv;
    rb[1 << CINSH]     += (f0 * g1 * g2) * xv;
    rb[5 << CINSH]     += (g0 * f1 * g2) * xv;
    rb[6 << CINSH]     += (f0 * f1 * g2) * xv;
    rb[25 << CINSH]    += (g0 * g1 * f2) * xv;
    rb[26 << CINSH]    += (f0 * g1 * f2) * xv;
    rb[30 << CINSH]    += (g0 * f1 * f2) * xv;
    rb[31 << CINSH]    += (f0 * f1 * f2) * xv;
  }
  __syncthreads();
  const int RQ = KSG / 4;
  for (int t = tid; t < G * RQ; t += NT) {
    int r = t / RQ, c4 = t % RQ;
    int c = c4 * 4;
    float4 v = make_float4(0.0f, 0.0f, 0.0f, 0.0f);
    if (c < KDIM) v = *(const float4*)&rows[r * KDIM + c];
    ((float4*)&A[(size_t)(n0 + r) * KSG])[c4] = v;
  }
}

// ---------------- GEMM v3 ----------------
template <int BM, int COUT, int NT>
__global__ __launch_bounds__(NT) void gemm3_kernel(
    const float* __restrict__ A, const float* __restrict__ W,
    float* __restrict__ gpart, int M, int Kdim, int KS, int ktiles) {
  const int BK = 32;
  __shared__ float At[BK][BM + 4];
  __shared__ float Wl[BK][COUT];
  const int TC = COUT / 4;
  int tid = threadIdx.x;
  int tc = tid % TC;
  int tr = tid / TC;
  int m0 = blockIdx.x * BM;
  int kbeg = blockIdx.y * ktiles * BK;
  int kend = min(KS, kbeg + ktiles * BK);
  float ar[4][4];
#pragma unroll
  for (int i = 0; i < 4; i++)
#pragma unroll
    for (int j = 0; j < 4; j++) ar[i][j] = 0.0f;

  for (int k0 = kbeg; k0 < kend; k0 += BK) {
    for (int t = tid; t < BM * (BK / 4); t += NT) {
      int c4 = t % (BK / 4), r = t / (BK / 4);
      int m = m0 + r;
      float4 v = make_float4(0.0f, 0.0f, 0.0f, 0.0f);
      if (m < M) v = *(const float4*)&A[(size_t)m * KS + k0 + c4 * 4];
      At[c4 * 4 + 0][r] = v.x; At[c4 * 4 + 1][r] = v.y;
      At[c4 * 4 + 2][r] = v.z; At[c4 * 4 + 3][r] = v.w;
    }
    int kleft = Kdim - k0;
    if (kleft >= BK) {
      for (int t = tid; t < BK * COUT / 4; t += NT)
        ((float4*)&Wl[0][0])[t] = ((const float4*)&W[(size_t)k0 * COUT])[t];
    } else {
      for (int t = tid; t < BK * COUT; t += NT) {
        int kk = t / COUT, o = t % COUT;
        Wl[kk][o] = (kk < kleft) ? W[(size_t)(k0 + kk) * COUT + o] : 0.0f;
      }
    }
    __syncthreads();
#pragma unroll
    for (int kk = 0; kk < BK; kk++) {
      float4 a = *(const float4*)&At[kk][tr * 4];
      float4 w = *(const float4*)&Wl[kk][tc * 4];
      float av[4] = {a.x, a.y, a.z, a.w};
      float wv[4] = {w.x, w.y, w.z, w.w};
#pragma unroll
      for (int i = 0; i < 4; i++)
#pragma unroll
        for (int j = 0; j < 4; j++)
          ar[i][j] = fmaf(av[i], wv[j], ar[i][j]);
    }
    __syncthreads();
  }
  float* gp = gpart + ((size_t)blockIdx.y * M) * COUT + tc * 4;
#pragma unroll
  for (int i = 0; i < 4; i++) {
    int m = m0 + tr * 4 + i;
    if (m < M)
      *(float4*)(gp + (size_t)m * COUT) =
          make_float4(ar[i][0], ar[i][1], ar[i][2], ar[i][3]);
  }
}

// ---------------- epilogue ----------------
__global__ __launch_bounds__(256) void epilogue_kernel(
    const float* __restrict__ gpart, const int* __restrict__ degI,
    const float* __restrict__ x, const float* __restrict__ R,
    const float* __restrict__ b, float* __restrict__ h,
    int N, int Cin, int coutShift, int kchunks) {
  int tid = blockIdx.x * 256 + threadIdx.x;
  int Cout = 1 << coutShift;
  if (tid >= (N << coutShift)) return;
  int n = tid >> coutShift;
  int o = tid & (Cout - 1);
  size_t stride = (size_t)N << coutShift;
  float s = 0.0f;
  for (int c = 0; c < kchunks; c++) s += gpart[(size_t)c * stride + tid];
  s /= (float)max(degI[n], 1);
  float r = b[o];
  const float* xr = &x[n * Cin];
  for (int i = 0; i < Cin; i++) r = fmaf(xr[i], R[i * Cout + o], r);
  float v = s + r;
  h[tid] = v > 0.0f ? v : expm1f(v);
}

// ---------------- pool v5c: named-float4 accumulators, h tile in LDS, n unroll 8 ----------------
#define FMA4(c, pj, h) \
  c.x = fmaf(pj, h.x, c.x); c.y = fmaf(pj, h.y, c.y); \
  c.z = fmaf(pj, h.z, c.z); c.w = fmaf(pj, h.w, c.w);

template <int COUT, int OPT>
__global__ __launch_bounds__(256) void pool5c_kernel(
    const float* __restrict__ P, const float* __restrict__ h,
    float* __restrict__ partial, int Nsrc, int Nnext, int chunk, int items) {
  extern __shared__ float hs[];
  int c = blockIdx.y;
  int n0 = c * chunk;
  int n1 = min(Nsrc, n0 + chunk);
  int len = n1 - n0;
  for (int t = threadIdx.x; t < len * (COUT / 4); t += 256)
    ((float4*)hs)[t] = ((const float4*)&h[(size_t)n0 * COUT])[t];
  __syncthreads();
  int item = blockIdx.x * 256 + threadIdx.x;
  if (item >= items) return;
  int nj4 = Nnext >> 2;
  int j0 = (item % nj4) << 2;
  int o0 = (item / nj4) * OPT;
  const float4 z = make_float4(0.0f, 0.0f, 0.0f, 0.0f);
  float4 c00 = z, c01 = z, c02 = z, c03 = z;
  float4 c10 = z, c11 = z, c12 = z, c13 = z;
  float4 c20 = z, c21 = z, c22 = z, c23 = z;
  float4 c30 = z, c31 = z, c32 = z, c33 = z;
  const float* Pb = P + j0;

#define USTEP(pv, nn)                                                    \
  {                                                                      \
    const float4* hr = (const float4*)&hs[(nn) * COUT + o0];             \
    float4 h0 = hr[0], h1 = hr[1];                                       \
    FMA4(c00, pv.x, h0) FMA4(c01, pv.x, h1)                              \
    FMA4(c10, pv.y, h0) FMA4(c11, pv.y, h1)                              \
    FMA4(c20, pv.z, h0) FMA4(c21, pv.z, h1)                              \
    FMA4(c30, pv.w, h0) FMA4(c31, pv.w, h1)                              \
    if constexpr (OPT == 16) {                                           \
      float4 h2 = hr[2], h3 = hr[3];                                     \
      FMA4(c02, pv.x, h2) FMA4(c03, pv.x, h3)                            \
      FMA4(c12, pv.y, h2) FMA4(c13, pv.y, h3)                            \
      FMA4(c22, pv.z, h2) FMA4(c23, pv.z, h3)                            \
      FMA4(c32, pv.w, h2) FMA4(c33, pv.w, h3)                            \
    }                                                                    \
  }

  int n = 0;
  for (; n + 8 <= len; n += 8) {
    float4 pv0 = *(const float4*)&Pb[(size_t)(n0 + n + 0) * Nnext];
    float4 pv1 = *(const float4*)&Pb[(size_t)(n0 + n + 1) * Nnext];
    float4 pv2 = *(const float4*)&Pb[(size_t)(n0 + n + 2) * Nnext];
    float4 pv3 = *(const float4*)&Pb[(size_t)(n0 + n + 3) * Nnext];
    float4 pv4 = *(const float4*)&Pb[(size_t)(n0 + n + 4) * Nnext];
    float4 pv5 = *(const float4*)&Pb[(size_t)(n0 + n + 5) * Nnext];
    float4 pv6 = *(const float4*)&Pb[(size_t)(n0 + n + 6) * Nnext];
    float4 pv7 = *(const float4*)&Pb[(size_t)(n0 + n + 7) * Nnext];
    USTEP(pv0, n + 0)
    USTEP(pv1, n + 1)
    USTEP(pv2, n + 2)
    USTEP(pv3, n + 3)
    USTEP(pv4, n + 4)
    USTEP(pv5, n + 5)
    USTEP(pv6, n + 6)
    USTEP(pv7, n + 7)
  }
  for (; n < len; n++) {
    float4 pv = *(const float4*)&Pb[(size_t)(n0 + n) * Nnext];
    USTEP(pv, n)
  }
#undef USTEP

  float* pp = partial + ((size_t)c * Nnext + j0) * COUT + o0;
  *(float4*)(pp + 0 * COUT + 0) = c00;
  *(float4*)(pp + 0 * COUT + 4) = c01;
  *(float4*)(pp + 1 * COUT + 0) = c10;
  *(float4*)(pp + 1 * COUT + 4) = c11;
  *(float4*)(pp + 2 * COUT + 0) = c20;
  *(float4*)(pp + 2 * COUT + 4) = c21;
  *(float4*)(pp + 3 * COUT + 0) = c30;
  *(float4*)(pp + 3 * COUT + 4) = c31;
  if constexpr (OPT == 16) {
    *(float4*)(pp + 0 * COUT + 8)  = c02;
    *(float4*)(pp + 0 * COUT + 12) = c03;
    *(float4*)(pp + 1 * COUT + 8)  = c12;
    *(float4*)(pp + 1 * COUT + 12) = c13;
    *(float4*)(pp + 2 * COUT + 8)  = c22;
    *(float4*)(pp + 2 * COUT + 12) = c23;
    *(float4*)(pp + 3 * COUT + 8)  = c32;
    *(float4*)(pp + 3 * COUT + 12) = c33;
  }
}

// ---------------- pool reduce ----------------
__global__ __launch_bounds__(256) void preduce_kernel(
    const float* __restrict__ partial, float* __restrict__ xnext,
    int NnCout, int chunks) {
  int i = blockIdx.x * 256 + threadIdx.x;
  if (i >= NnCout) return;
  float s = 0.0f;
  for (int c = 0; c < chunks; c++) s += partial[(size_t)c * NnCout + i];
  xnext[i] = s;
}

// ---------------- final max ----------------
__global__ __launch_bounds__(128) void max_kernel(const float* __restrict__ x6,
                                                  float* __restrict__ out) {
  int o = threadIdx.x;
  float m = -3.0e38f;
  for (int n = 0; n < 16; n++) m = fmaxf(m, x6[n * 128 + o]);
  out[o] = m;
}

extern "C" void kernel_launch(void* const* d_in, const int* in_sizes, int n_in,
                              void* d_out, int out_size, void* d_ws, size_t ws_size,
                              hipStream_t stream) {
  static const int NSh[7] = {20000, 5000, 1280, 320, 80, 32, 16};
  static const int NFh[7] = {2, 16, 32, 64, 128, 128, 128};
  static const int cinSh[6]  = {1, 4, 5, 6, 7, 7};
  static const int coutSh[6] = {4, 5, 6, 7, 7, 7};
  static const int KSt[6] = {256, 2016, 4000, 8000, 16000, 16000};
  static const int kchunksTab[6] = {4, 8, 16, 32, 32, 64};
  static const int ktilesTab[6]  = {2, 8, 8, 8, 16, 8};
  static const int poolChunksTab[6] = {120, 80, 16, 8, 4, 2};
  static const int histOff[6] = {0, 20000, 25000, 26280, 26600, 26680};

  const float* x0 = (const float*)d_in[0];
  Ptr6i eis;
  Ptr6f eas;
  for (int l = 0; l < 6; l++) {
    eis.p[l] = (const int*)d_in[1 + 2 * l];
    eas.p[l] = (const float*)d_in[2 + 2 * l];
  }
  const float* Pm[6];
  for (int l = 0; l < 6; l++) Pm[l] = (const float*)d_in[13 + l];
  const float* Wt[6];
  const float* Rt[6];
  const float* bt[6];
  for (int l = 0; l < 6; l++) {
    Wt[l] = (const float*)d_in[19 + 3 * l];
    Rt[l] = (const float*)d_in[20 + 3 * l];
    bt[l] = (const float*)d_in[21 + 3 * l];
  }

  float* ws = (float*)d_ws;
  float* A     = ws;                       // max N*KS = 10.08M (L1+)
  float* gpart = ws + 10150000;            // max 1.31M
  float* hbuf  = ws + 11500000;            // 320000
  float* ppart = ws + 12000000;            // max 120*5000*16 = 9.6M
  float* xA    = ws + 32100000;
  float* xB    = ws + 32200000;
  int* cnt     = (int*)(ws + 32300000);    // 26712 (-> deg)
  float4* recS = (float4*)(ws + 33000000); // 26712*64 recs = 27.4MB

  // ONE-pass bucketed CSR
  hipMemsetAsync(cnt, 0, 26712 * sizeof(int), stream);
  fill_all_kernel<<<1670, 256, 0, stream>>>(eis, eas, cnt, recS);

  const float* cur = x0;
  for (int l = 0; l < 6; l++) {
    int N = NSh[l], Nn = NSh[l + 1], Cin = NFh[l], Cout = NFh[l + 1];
    int Kdim = NKER * Cin, KS = KSt[l];
    float* xnext = (l & 1) ? xB : xA;
    const int* cntL = cnt + histOff[l];
    const float4* rc = recS + (size_t)histOff[l] * CAP;

    if (l == 0) {
      // fully fused direct conv + epilogue -> hbuf
      conv0_kernel<<<(N + 127) / 128, 128, 0, stream>>>(
          cntL, rc, cur, Wt[0], Rt[0], bt[0], hbuf, N);
    } else {
      switch (l) {
        case 1: build4_kernel<4, 8, 2000, 2016, 128><<<625, 128, 0, stream>>>(cntL, rc, cur, A); break;
        case 2: build4_kernel<5, 4, 4000, 4000, 128><<<320, 128, 0, stream>>>(cntL, rc, cur, A); break;
        case 3: build4_kernel<6, 2, 8000, 8000, 128><<<160, 128, 0, stream>>>(cntL, rc, cur, A); break;
        case 4: build4_kernel<7, 1, 16000, 16000, 128><<<80, 128, 0, stream>>>(cntL, rc, cur, A); break;
        default: build4_kernel<7, 1, 16000, 16000, 128><<<32, 128, 0, stream>>>(cntL, rc, cur, A); break;
      }
      int kchunks = kchunksTab[l], ktiles = ktilesTab[l];
      switch (l) {
        case 1: {
          dim3 g((N + 127) / 128, kchunks);
          gemm3_kernel<128, 32, 256><<<g, 256, 0, stream>>>(A, Wt[l], gpart, N, Kdim, KS, ktiles);
          break;
        }
        case 2: {
          dim3 g((N + 63) / 64, kchunks);
          gemm3_kernel<64, 64, 256><<<g, 256, 0, stream>>>(A, Wt[l], gpart, N, Kdim, KS, ktiles);
          break;
        }
        default: {
          dim3 g((N + 31) / 32, kchunks);
          gemm3_kernel<32, 128, 256><<<g, 256, 0, stream>>>(A, Wt[l], gpart, N, Kdim, KS, ktiles);
          break;
        }
      }
      int ethreads = N << coutSh[l];
      epilogue_kernel<<<(ethreads + 255) / 256, 256, 0, stream>>>(
          gpart, cntL, cur, Rt[l], bt[l], hbuf, N, Cin, coutSh[l], kchunks);
    }

    int pc = poolChunksTab[l];
    int chunk = (N + pc - 1) / pc;
    size_t ldsB = (size_t)chunk * Cout * sizeof(float);
    int items, gx;
    switch (Cout) {
      case 16:
        items = (Nn >> 2) * 1;
        gx = (items + 255) / 256;
        pool5c_kernel<16, 16><<<dim3(gx, pc), 256, ldsB, stream>>>(Pm[l], hbuf, ppart, N, Nn, chunk, items);
        break;
      case 32:
        items = (Nn >> 2) * 2;
        gx = (items + 255) / 256;
        pool5c_kernel<32, 16><<<dim3(gx, pc), 256, ldsB, stream>>>(Pm[l], hbuf, ppart, N, Nn, chunk, items);
        break;
      case 64:
        items = (Nn >> 2) * 8;
        gx = (items + 255) / 256;
        pool5c_kernel<64, 8><<<dim3(gx, pc), 256, ldsB, stream>>>(Pm[l], hbuf, ppart, N, Nn, chunk, items);
        break;
      default:
        items = (Nn >> 2) * 16;
        gx = (items + 255) / 256;
        pool5c_kernel<128, 8><<<dim3(gx, pc), 256, ldsB, stream>>>(Pm[l], hbuf, ppart, N, Nn, chunk, items);
        break;
    }
    int NnCout = Nn << coutSh[l];
    preduce_kernel<<<(NnCout + 255) / 256, 256, 0, stream>>>(ppart, xnext, NnCout, pc);

    cur = xnext;
  }

  max_kernel<<<1, 128, 0, stream>>>(cur, (float*)d_out);
}

// Round 18
// 705.766 us; speedup vs baseline: 1.0209x; 1.0209x over previous
//
#include <hip/hip_runtime.h>
#include <math.h>

#define NKER 125
#define CAP 64

struct Ptr6i { const int* p[6]; };
struct Ptr6f { const float* p[6]; };

// ---------------- fill_all v2: rec stored COALESCED at edge order; only 4B idx scattered ----------------
__global__ __launch_bounds__(256) void fill_all_kernel(
    Ptr6i eis, Ptr6f eas, int* __restrict__ cnt, int* __restrict__ idx,
    float4* __restrict__ recE) {
  static const int EB[7] = {0, 1250, 1563, 1643, 1663, 1668, 1670};
  static const int Es[6] = {320000, 80000, 20480, 5120, 1280, 512};
  static const int hOff[6] = {0, 20000, 25000, 26280, 26600, 26680};
  static const int EoffK[6] = {0, 320000, 400000, 420480, 425600, 426880};
  int b = blockIdx.x;
  int l = 0;
  while (b >= EB[l + 1]) l++;
  int e = (b - EB[l]) * 256 + threadIdx.x;
  if (e >= Es[l]) return;
  const int* ei = eis.p[l];
  const float* ea = eas.p[l];
  int src = ei[e];
  int dst = ei[Es[l] + e];
  int kpk = 0;
  float f[3];
#pragma unroll
  for (int d = 0; d < 3; d++) {
    float p = ea[e * 3 + d] * 4.0f;
    float kf = fminf(fmaxf(floorf(p), 0.0f), 3.0f);
    f[d] = p - kf;
    kpk |= ((int)kf) << (4 * d);
  }
  // coalesced 16B record store
  recE[EoffK[l] + e] =
      make_float4(__uint_as_float((unsigned)src | ((unsigned)kpk << 15)), f[0], f[1], f[2]);
  // 4B scattered index store
  int node = hOff[l] + dst;
  int r = atomicAdd(&cnt[node], 1);
  if (r < CAP) idx[(size_t)node * CAP + r] = e;
}

// ---------------- build5 generic: thread owns (node, ci); idx -> recE gather; plain LDS RMW ----------------
template <int CINSH, int G, int KDIM, int KSG, int NT>
__global__ __launch_bounds__(NT) void build5_kernel(
    const int* __restrict__ cntL, const int* __restrict__ idxL,
    const float4* __restrict__ recE, const float* __restrict__ x,
    float* __restrict__ A) {
  __shared__ float rows[G * KDIM];
  const int Cin = 1 << CINSH;
  int tid = threadIdx.x;
  int n0 = blockIdx.x * G;
  for (int t = tid; t < G * KDIM / 4; t += NT)
    ((float4*)rows)[t] = make_float4(0.0f, 0.0f, 0.0f, 0.0f);
  __syncthreads();
  int nl = tid >> CINSH;
  int ci = tid & (Cin - 1);
  int n = n0 + nl;
  int m = min(cntL[n], CAP);
  const int* ix = idxL + (size_t)n * CAP;
  float* row = rows + nl * KDIM + ci;
  for (int i = 0; i < m; i++) {
    float4 rec = recE[ix[i]];
    unsigned v = __float_as_uint(rec.x);
    int src = v & 0x7fff;
    int kpk = v >> 15;
    float f0 = rec.y, f1 = rec.z, f2 = rec.w;
    float xv = x[((size_t)src << CINSH) + ci];
    float g0 = 1.0f - f0, g1 = 1.0f - f1, g2 = 1.0f - f2;
    int kb = (kpk & 15) + 5 * ((kpk >> 4) & 15) + 25 * ((kpk >> 8) & 15);
    float* rb = row + (kb << CINSH);
    rb[0]              += (g0 * g1 * g2) * xv;
    rb[1 << CINSH]     += (f0 * g1 * g2) * xv;
    rb[5 << CINSH]     += (g0 * f1 * g2) * xv;
    rb[6 << CINSH]     += (f0 * f1 * g2) * xv;
    rb[25 << CINSH]    += (g0 * g1 * f2) * xv;
    rb[26 << CINSH]    += (f0 * g1 * f2) * xv;
    rb[30 << CINSH]    += (g0 * f1 * f2) * xv;
    rb[31 << CINSH]    += (f0 * f1 * f2) * xv;
  }
  __syncthreads();
  const int RQ = KSG / 4;
  for (int t = tid; t < G * RQ; t += NT) {
    int r = t / RQ, c4 = t % RQ;
    int c = c4 * 4;
    float4 v = make_float4(0.0f, 0.0f, 0.0f, 0.0f);
    if (c < KDIM) v = *(const float4*)&rows[r * KDIM + c];
    ((float4*)&A[(size_t)(n0 + r) * KSG])[c4] = v;
  }
}

// ---------------- build5 L0: Cin=2, (node,ci) split, 128 threads, stride-254 rows ----------------
__global__ __launch_bounds__(128) void build5_l0_kernel(
    const int* __restrict__ cntL, const int* __restrict__ idxL,
    const float4* __restrict__ recE, const float* __restrict__ x,
    float* __restrict__ A, int N) {
  __shared__ float rows[64 * 254];
  int tid = threadIdx.x;
  int n0 = blockIdx.x * 64;
  for (int t = tid; t < 64 * 254 / 4; t += 128)
    ((float4*)rows)[t] = make_float4(0.0f, 0.0f, 0.0f, 0.0f);
  __syncthreads();
  int nl = tid >> 1;
  int ci = tid & 1;
  int n = n0 + nl;
  if (n < N) {
    int m = min(cntL[n], CAP);
    const int* ix = idxL + (size_t)n * CAP;
    float* row = rows + nl * 254 + ci;
    for (int i = 0; i < m; i++) {
      float4 rec = recE[ix[i]];
      unsigned v = __float_as_uint(rec.x);
      int src = v & 0x7fff;
      int kpk = v >> 15;
      float f0 = rec.y, f1 = rec.z, f2 = rec.w;
      float xv = x[(size_t)src * 2 + ci];
      float g0 = 1.0f - f0, g1 = 1.0f - f1, g2 = 1.0f - f2;
      int kb = (kpk & 15) + 5 * ((kpk >> 4) & 15) + 25 * ((kpk >> 8) & 15);
      float* rb = row + kb * 2;
      rb[0]  = fmaf(g0 * g1 * g2, xv, rb[0]);
      rb[2]  = fmaf(f0 * g1 * g2, xv, rb[2]);
      rb[10] = fmaf(g0 * f1 * g2, xv, rb[10]);
      rb[12] = fmaf(f0 * f1 * g2, xv, rb[12]);
      rb[50] = fmaf(g0 * g1 * f2, xv, rb[50]);
      rb[52] = fmaf(f0 * g1 * f2, xv, rb[52]);
      rb[60] = fmaf(g0 * f1 * f2, xv, rb[60]);
      rb[62] = fmaf(f0 * f1 * f2, xv, rb[62]);
    }
  }
  __syncthreads();
  for (int it = 0; it < 32; it++) {
    int sub = tid >> 6;
    int c4 = tid & 63;
    int nn = n0 + it * 2 + sub;
    if (nn >= N) continue;
    float4 v = make_float4(0.0f, 0.0f, 0.0f, 0.0f);
    if (c4 < 63) v = *(const float4*)&rows[(it * 2 + sub) * 254 + c4 * 4];
    ((float4*)&A[(size_t)nn * 256])[c4] = v;
  }
}

// ---------------- GEMM v3 ----------------
template <int BM, int COUT, int NT>
__global__ __launch_bounds__(NT) void gemm3_kernel(
    const float* __restrict__ A, const float* __restrict__ W,
    float* __restrict__ gpart, int M, int Kdim, int KS, int ktiles) {
  const int BK = 32;
  __shared__ float At[BK][BM + 4];
  __shared__ float Wl[BK][COUT];
  const int TC = COUT / 4;
  int tid = threadIdx.x;
  int tc = tid % TC;
  int tr = tid / TC;
  int m0 = blockIdx.x * BM;
  int kbeg = blockIdx.y * ktiles * BK;
  int kend = min(KS, kbeg + ktiles * BK);
  float ar[4][4];
#pragma unroll
  for (int i = 0; i < 4; i++)
#pragma unroll
    for (int j = 0; j < 4; j++) ar[i][j] = 0.0f;

  for (int k0 = kbeg; k0 < kend; k0 += BK) {
    for (int t = tid; t < BM * (BK / 4); t += NT) {
      int c4 = t % (BK / 4), r = t / (BK / 4);
      int m = m0 + r;
      float4 v = make_float4(0.0f, 0.0f, 0.0f, 0.0f);
      if (m < M) v = *(const float4*)&A[(size_t)m * KS + k0 + c4 * 4];
      At[c4 * 4 + 0][r] = v.x; At[c4 * 4 + 1][r] = v.y;
      At[c4 * 4 + 2][r] = v.z; At[c4 * 4 + 3][r] = v.w;
    }
    int kleft = Kdim - k0;
    if (kleft >= BK) {
      for (int t = tid; t < BK * COUT / 4; t += NT)
        ((float4*)&Wl[0][0])[t] = ((const float4*)&W[(size_t)k0 * COUT])[t];
    } else {
      for (int t = tid; t < BK * COUT; t += NT) {
        int kk = t / COUT, o = t % COUT;
        Wl[kk][o] = (kk < kleft) ? W[(size_t)(k0 + kk) * COUT + o] : 0.0f;
      }
    }
    __syncthreads();
#pragma unroll
    for (int kk = 0; kk < BK; kk++) {
      float4 a = *(const float4*)&At[kk][tr * 4];
      float4 w = *(const float4*)&Wl[kk][tc * 4];
      float av[4] = {a.x, a.y, a.z, a.w};
      float wv[4] = {w.x, w.y, w.z, w.w};
#pragma unroll
      for (int i = 0; i < 4; i++)
#pragma unroll
        for (int j = 0; j < 4; j++)
          ar[i][j] = fmaf(av[i], wv[j], ar[i][j]);
    }
    __syncthreads();
  }
  float* gp = gpart + ((size_t)blockIdx.y * M) * COUT + tc * 4;
#pragma unroll
  for (int i = 0; i < 4; i++) {
    int m = m0 + tr * 4 + i;
    if (m < M)
      *(float4*)(gp + (size_t)m * COUT) =
          make_float4(ar[i][0], ar[i][1], ar[i][2], ar[i][3]);
  }
}

// ---------------- epilogue ----------------
__global__ __launch_bounds__(256) void epilogue_kernel(
    const float* __restrict__ gpart, const int* __restrict__ degI,
    const float* __restrict__ x, const float* __restrict__ R,
    const float* __restrict__ b, float* __restrict__ h,
    int N, int Cin, int coutShift, int kchunks) {
  int tid = blockIdx.x * 256 + threadIdx.x;
  int Cout = 1 << coutShift;
  if (tid >= (N << coutShift)) return;
  int n = tid >> coutShift;
  int o = tid & (Cout - 1);
  size_t stride = (size_t)N << coutShift;
  float s = 0.0f;
  for (int c = 0; c < kchunks; c++) s += gpart[(size_t)c * stride + tid];
  s /= (float)max(degI[n], 1);
  float r = b[o];
  const float* xr = &x[n * Cin];
  for (int i = 0; i < Cin; i++) r = fmaf(xr[i], R[i * Cout + o], r);
  float v = s + r;
  h[tid] = v > 0.0f ? v : expm1f(v);
}

// ---------------- pool v5c: named-float4 accumulators, h tile in LDS, n unroll 8 ----------------
#define FMA4(c, pj, h) \
  c.x = fmaf(pj, h.x, c.x); c.y = fmaf(pj, h.y, c.y); \
  c.z = fmaf(pj, h.z, c.z); c.w = fmaf(pj, h.w, c.w);

template <int COUT, int OPT>
__global__ __launch_bounds__(256) void pool5c_kernel(
    const float* __restrict__ P, const float* __restrict__ h,
    float* __restrict__ partial, int Nsrc, int Nnext, int chunk, int items) {
  extern __shared__ float hs[];
  int c = blockIdx.y;
  int n0 = c * chunk;
  int n1 = min(Nsrc, n0 + chunk);
  int len = n1 - n0;
  for (int t = threadIdx.x; t < len * (COUT / 4); t += 256)
    ((float4*)hs)[t] = ((const float4*)&h[(size_t)n0 * COUT])[t];
  __syncthreads();
  int item = blockIdx.x * 256 + threadIdx.x;
  if (item >= items) return;
  int nj4 = Nnext >> 2;
  int j0 = (item % nj4) << 2;
  int o0 = (item / nj4) * OPT;
  const float4 z = make_float4(0.0f, 0.0f, 0.0f, 0.0f);
  float4 c00 = z, c01 = z, c02 = z, c03 = z;
  float4 c10 = z, c11 = z, c12 = z, c13 = z;
  float4 c20 = z, c21 = z, c22 = z, c23 = z;
  float4 c30 = z, c31 = z, c32 = z, c33 = z;
  const float* Pb = P + j0;

#define USTEP(pv, nn)                                                    \
  {                                                                      \
    const float4* hr = (const float4*)&hs[(nn) * COUT + o0];             \
    float4 h0 = hr[0], h1 = hr[1];                                       \
    FMA4(c00, pv.x, h0) FMA4(c01, pv.x, h1)                              \
    FMA4(c10, pv.y, h0) FMA4(c11, pv.y, h1)                              \
    FMA4(c20, pv.z, h0) FMA4(c21, pv.z, h1)                              \
    FMA4(c30, pv.w, h0) FMA4(c31, pv.w, h1)                              \
    if constexpr (OPT == 16) {                                           \
      float4 h2 = hr[2], h3 = hr[3];                                     \
      FMA4(c02, pv.x, h2) FMA4(c03, pv.x, h3)                            \
      FMA4(c12, pv.y, h2) FMA4(c13, pv.y, h3)                            \
      FMA4(c22, pv.z, h2) FMA4(c23, pv.z, h3)                            \
      FMA4(c32, pv.w, h2) FMA4(c33, pv.w, h3)                            \
    }                                                                    \
  }

  int n = 0;
  for (; n + 8 <= len; n += 8) {
    float4 pv0 = *(const float4*)&Pb[(size_t)(n0 + n + 0) * Nnext];
    float4 pv1 = *(const float4*)&Pb[(size_t)(n0 + n + 1) * Nnext];
    float4 pv2 = *(const float4*)&Pb[(size_t)(n0 + n + 2) * Nnext];
    float4 pv3 = *(const float4*)&Pb[(size_t)(n0 + n + 3) * Nnext];
    float4 pv4 = *(const float4*)&Pb[(size_t)(n0 + n + 4) * Nnext];
    float4 pv5 = *(const float4*)&Pb[(size_t)(n0 + n + 5) * Nnext];
    float4 pv6 = *(const float4*)&Pb[(size_t)(n0 + n + 6) * Nnext];
    float4 pv7 = *(const float4*)&Pb[(size_t)(n0 + n + 7) * Nnext];
    USTEP(pv0, n + 0)
    USTEP(pv1, n + 1)
    USTEP(pv2, n + 2)
    USTEP(pv3, n + 3)
    USTEP(pv4, n + 4)
    USTEP(pv5, n + 5)
    USTEP(pv6, n + 6)
    USTEP(pv7, n + 7)
  }
  for (; n < len; n++) {
    float4 pv = *(const float4*)&Pb[(size_t)(n0 + n) * Nnext];
    USTEP(pv, n)
  }
#undef USTEP

  float* pp = partial + ((size_t)c * Nnext + j0) * COUT + o0;
  *(float4*)(pp + 0 * COUT + 0) = c00;
  *(float4*)(pp + 0 * COUT + 4) = c01;
  *(float4*)(pp + 1 * COUT + 0) = c10;
  *(float4*)(pp + 1 * COUT + 4) = c11;
  *(float4*)(pp + 2 * COUT + 0) = c20;
  *(float4*)(pp + 2 * COUT + 4) = c21;
  *(float4*)(pp + 3 * COUT + 0) = c30;
  *(float4*)(pp + 3 * COUT + 4) = c31;
  if constexpr (OPT == 16) {
    *(float4*)(pp + 0 * COUT + 8)  = c02;
    *(float4*)(pp + 0 * COUT + 12) = c03;
    *(float4*)(pp + 1 * COUT + 8)  = c12;
    *(float4*)(pp + 1 * COUT + 12) = c13;
    *(float4*)(pp + 2 * COUT + 8)  = c22;
    *(float4*)(pp + 2 * COUT + 12) = c23;
    *(float4*)(pp + 3 * COUT + 8)  = c32;
    *(float4*)(pp + 3 * COUT + 12) = c33;
  }
}

// ---------------- pool reduce ----------------
__global__ __launch_bounds__(256) void preduce_kernel(
    const float* __restrict__ partial, float* __restrict__ xnext,
    int NnCout, int chunks) {
  int i = blockIdx.x * 256 + threadIdx.x;
  if (i >= NnCout) return;
  float s = 0.0f;
  for (int c = 0; c < chunks; c++) s += partial[(size_t)c * NnCout + i];
  xnext[i] = s;
}

// ---------------- final max ----------------
__global__ __launch_bounds__(128) void max_kernel(const float* __restrict__ x6,
                                                  float* __restrict__ out) {
  int o = threadIdx.x;
  float m = -3.0e38f;
  for (int n = 0; n < 16; n++) m = fmaxf(m, x6[n * 128 + o]);
  out[o] = m;
}

extern "C" void kernel_launch(void* const* d_in, const int* in_sizes, int n_in,
                              void* d_out, int out_size, void* d_ws, size_t ws_size,
                              hipStream_t stream) {
  static const int NSh[7] = {20000, 5000, 1280, 320, 80, 32, 16};
  static const int NFh[7] = {2, 16, 32, 64, 128, 128, 128};
  static const int cinSh[6]  = {1, 4, 5, 6, 7, 7};
  static const int coutSh[6] = {4, 5, 6, 7, 7, 7};
  static const int KSt[6] = {256, 2016, 4000, 8000, 16000, 16000};
  static const int kchunksTab[6] = {4, 8, 16, 32, 64, 128};
  static const int ktilesTab[6]  = {2, 8, 8, 8, 8, 4};
  static const int poolChunksTab[6] = {120, 80, 16, 8, 4, 2};
  static const int histOff[6] = {0, 20000, 25000, 26280, 26600, 26680};
  static const int Eoff[6] = {0, 320000, 400000, 420480, 425600, 426880};

  const float* x0 = (const float*)d_in[0];
  Ptr6i eis;
  Ptr6f eas;
  for (int l = 0; l < 6; l++) {
    eis.p[l] = (const int*)d_in[1 + 2 * l];
    eas.p[l] = (const float*)d_in[2 + 2 * l];
  }
  const float* Pm[6];
  for (int l = 0; l < 6; l++) Pm[l] = (const float*)d_in[13 + l];
  const float* Wt[6];
  const float* Rt[6];
  const float* bt[6];
  for (int l = 0; l < 6; l++) {
    Wt[l] = (const float*)d_in[19 + 3 * l];
    Rt[l] = (const float*)d_in[20 + 3 * l];
    bt[l] = (const float*)d_in[21 + 3 * l];
  }

  float* ws = (float*)d_ws;
  float* A     = ws;                       // max N*KS = 10.08M
  float* gpart = ws + 10150000;            // max 1.31M
  float* hbuf  = ws + 11500000;            // 320000
  float* ppart = ws + 12000000;            // max 120*5000*16 = 9.6M
  float* xA    = ws + 32100000;
  float* xB    = ws + 32200000;
  int* cnt     = (int*)(ws + 32300000);    // 26712 (-> deg)
  float4* recE = (float4*)(ws + 33000000); // 427392 recs coalesced (6.8MB)
  int* idx     = (int*)(ws + 35000000);    // 26712*CAP ints (6.8MB)

  // ONE-pass bucketed CSR: coalesced rec store + 4B scattered index
  hipMemsetAsync(cnt, 0, 26712 * sizeof(int), stream);
  fill_all_kernel<<<1670, 256, 0, stream>>>(eis, eas, cnt, idx, recE);

  const float* cur = x0;
  for (int l = 0; l < 6; l++) {
    int N = NSh[l], Nn = NSh[l + 1], Cin = NFh[l], Cout = NFh[l + 1];
    int Kdim = NKER * Cin, KS = KSt[l];
    float* xnext = (l & 1) ? xB : xA;
    const int* cntL = cnt + histOff[l];
    const int* idxL = idx + (size_t)histOff[l] * CAP;
    const float4* rcE = recE + Eoff[l];

    switch (l) {
      case 0: build5_l0_kernel<<<313, 128, 0, stream>>>(cntL, idxL, rcE, cur, A, N); break;
      case 1: build5_kernel<4, 8, 2000, 2016, 128><<<625, 128, 0, stream>>>(cntL, idxL, rcE, cur, A); break;
      case 2: build5_kernel<5, 4, 4000, 4000, 128><<<320, 128, 0, stream>>>(cntL, idxL, rcE, cur, A); break;
      case 3: build5_kernel<6, 2, 8000, 8000, 128><<<160, 128, 0, stream>>>(cntL, idxL, rcE, cur, A); break;
      case 4: build5_kernel<7, 1, 16000, 16000, 128><<<80, 128, 0, stream>>>(cntL, idxL, rcE, cur, A); break;
      default: build5_kernel<7, 1, 16000, 16000, 128><<<32, 128, 0, stream>>>(cntL, idxL, rcE, cur, A); break;
    }

    int kchunks = kchunksTab[l], ktiles = ktilesTab[l];
    switch (l) {
      case 0: {
        dim3 g((N + 127) / 128, kchunks);
        gemm3_kernel<128, 16, 128><<<g, 128, 0, stream>>>(A, Wt[l], gpart, N, Kdim, KS, ktiles);
        break;
      }
      case 1: {
        dim3 g((N + 127) / 128, kchunks);
        gemm3_kernel<128, 32, 256><<<g, 256, 0, stream>>>(A, Wt[l], gpart, N, Kdim, KS, ktiles);
        break;
      }
      case 2: {
        dim3 g((N + 63) / 64, kchunks);
        gemm3_kernel<64, 64, 256><<<g, 256, 0, stream>>>(A, Wt[l], gpart, N, Kdim, KS, ktiles);
        break;
      }
      default: {
        dim3 g((N + 31) / 32, kchunks);
        gemm3_kernel<32, 128, 256><<<g, 256, 0, stream>>>(A, Wt[l], gpart, N, Kdim, KS, ktiles);
        break;
      }
    }

    int ethreads = N << coutSh[l];
    epilogue_kernel<<<(ethreads + 255) / 256, 256, 0, stream>>>(
        gpart, cntL, cur, Rt[l], bt[l], hbuf, N, Cin, coutSh[l], kchunks);

    int pc = poolChunksTab[l];
    int chunk = (N + pc - 1) / pc;
    size_t ldsB = (size_t)chunk * Cout * sizeof(float);
    int items, gx;
    switch (Cout) {
      case 16:
        items = (Nn >> 2) * 1;
        gx = (items + 255) / 256;
        pool5c_kernel<16, 16><<<dim3(gx, pc), 256, ldsB, stream>>>(Pm[l], hbuf, ppart, N, Nn, chunk, items);
        break;
      case 32:
        items = (Nn >> 2) * 2;
        gx = (items + 255) / 256;
        pool5c_kernel<32, 16><<<dim3(gx, pc), 256, ldsB, stream>>>(Pm[l], hbuf, ppart, N, Nn, chunk, items);
        break;
      case 64:
        items = (Nn >> 2) * 8;
        gx = (items + 255) / 256;
        pool5c_kernel<64, 8><<<dim3(gx, pc), 256, ldsB, stream>>>(Pm[l], hbuf, ppart, N, Nn, chunk, items);
        break;
      default:
        items = (Nn >> 2) * 16;
        gx = (items + 255) / 256;
        pool5c_kernel<128, 8><<<dim3(gx, pc), 256, ldsB, stream>>>(Pm[l], hbuf, ppart, N, Nn, chunk, items);
        break;
    }
    int NnCout = Nn << coutSh[l];
    preduce_kernel<<<(NnCout + 255) / 256, 256, 0, stream>>>(ppart, xnext, NnCout, pc);

    cur = xnext;
  }

  max_kernel<<<1, 128, 0, stream>>>(cur, (float*)d_out);
}

// Round 19
// 688.169 us; speedup vs baseline: 1.0470x; 1.0256x over previous
//
#include <hip/hip_runtime.h>
#include <math.h>

#define NKER 125
#define CAP 64

struct Ptr6i { const int* p[6]; };
struct Ptr6f { const float* p[6]; };

// ---------------- fill_all: ONE pass; r = atomicAdd(cnt[dst]); recS[dst*CAP+r] = packed rec ----------------
__global__ __launch_bounds__(256) void fill_all_kernel(
    Ptr6i eis, Ptr6f eas, int* __restrict__ cnt, float4* __restrict__ recS) {
  static const int EB[7] = {0, 1250, 1563, 1643, 1663, 1668, 1670};
  static const int Es[6] = {320000, 80000, 20480, 5120, 1280, 512};
  static const int hOff[6] = {0, 20000, 25000, 26280, 26600, 26680};
  int b = blockIdx.x;
  int l = 0;
  while (b >= EB[l + 1]) l++;
  int e = (b - EB[l]) * 256 + threadIdx.x;
  if (e >= Es[l]) return;
  const int* ei = eis.p[l];
  const float* ea = eas.p[l];
  int src = ei[e];
  int dst = ei[Es[l] + e];
  int kpk = 0;
  float f[3];
#pragma unroll
  for (int d = 0; d < 3; d++) {
    float p = ea[e * 3 + d] * 4.0f;
    float kf = fminf(fmaxf(floorf(p), 0.0f), 3.0f);
    f[d] = p - kf;
    kpk |= ((int)kf) << (4 * d);
  }
  int node = hOff[l] + dst;
  int r = atomicAdd(&cnt[node], 1);
  if (r < CAP)
    recS[(size_t)node * CAP + r] =
        make_float4(__uint_as_float((unsigned)src | ((unsigned)kpk << 15)), f[0], f[1], f[2]);
}

// ---------------- build4 generic: thread owns (node, ci); plain LDS RMW; bucketed recS ----------------
template <int CINSH, int G, int KDIM, int KSG, int NT>
__global__ __launch_bounds__(NT) void build4_kernel(
    const int* __restrict__ cntL, const float4* __restrict__ rc,
    const float* __restrict__ x, float* __restrict__ A) {
  __shared__ float rows[G * KDIM];
  const int Cin = 1 << CINSH;
  int tid = threadIdx.x;
  int n0 = blockIdx.x * G;
  for (int t = tid; t < G * KDIM / 4; t += NT)
    ((float4*)rows)[t] = make_float4(0.0f, 0.0f, 0.0f, 0.0f);
  __syncthreads();
  int nl = tid >> CINSH;
  int ci = tid & (Cin - 1);
  int n = n0 + nl;
  int m = min(cntL[n], CAP);
  const float4* re = rc + (size_t)n * CAP;
  float* row = rows + nl * KDIM + ci;
  for (int i = 0; i < m; i++) {
    float4 rec = re[i];
    unsigned v = __float_as_uint(rec.x);
    int src = v & 0x7fff;
    int kpk = v >> 15;
    float f0 = rec.y, f1 = rec.z, f2 = rec.w;
    float xv = x[((size_t)src << CINSH) + ci];
    float g0 = 1.0f - f0, g1 = 1.0f - f1, g2 = 1.0f - f2;
    int kb = (kpk & 15) + 5 * ((kpk >> 4) & 15) + 25 * ((kpk >> 8) & 15);
    float* rb = row + (kb << CINSH);
    rb[0]              += (g0 * g1 * g2) * xv;
    rb[1 << CINSH]     += (f0 * g1 * g2) * xv;
    rb[5 << CINSH]     += (g0 * f1 * g2) * xv;
    rb[6 << CINSH]     += (f0 * f1 * g2) * xv;
    rb[25 << CINSH]    += (g0 * g1 * f2) * xv;
    rb[26 << CINSH]    += (f0 * g1 * f2) * xv;
    rb[30 << CINSH]    += (g0 * f1 * f2) * xv;
    rb[31 << CINSH]    += (f0 * f1 * f2) * xv;
  }
  __syncthreads();
  const int RQ = KSG / 4;
  for (int t = tid; t < G * RQ; t += NT) {
    int r = t / RQ, c4 = t % RQ;
    int c = c4 * 4;
    float4 v = make_float4(0.0f, 0.0f, 0.0f, 0.0f);
    if (c < KDIM) v = *(const float4*)&rows[r * KDIM + c];
    ((float4*)&A[(size_t)(n0 + r) * KSG])[c4] = v;
  }
}

// ---------------- build4 L0: Cin=2, (node,ci) split, 128 threads, stride-254 rows ----------------
__global__ __launch_bounds__(128) void build4_l0_kernel(
    const int* __restrict__ cntL, const float4* __restrict__ rc,
    const float* __restrict__ x, float* __restrict__ A, int N) {
  __shared__ float rows[64 * 254];
  int tid = threadIdx.x;
  int n0 = blockIdx.x * 64;
  for (int t = tid; t < 64 * 254 / 4; t += 128)
    ((float4*)rows)[t] = make_float4(0.0f, 0.0f, 0.0f, 0.0f);
  __syncthreads();
  int nl = tid >> 1;
  int ci = tid & 1;
  int n = n0 + nl;
  if (n < N) {
    int m = min(cntL[n], CAP);
    const float4* re = rc + (size_t)n * CAP;
    float* row = rows + nl * 254 + ci;
    for (int i = 0; i < m; i++) {
      float4 rec = re[i];
      unsigned v = __float_as_uint(rec.x);
      int src = v & 0x7fff;
      int kpk = v >> 15;
      float f0 = rec.y, f1 = rec.z, f2 = rec.w;
      float xv = x[(size_t)src * 2 + ci];
      float g0 = 1.0f - f0, g1 = 1.0f - f1, g2 = 1.0f - f2;
      int kb = (kpk & 15) + 5 * ((kpk >> 4) & 15) + 25 * ((kpk >> 8) & 15);
      float* rb = row + kb * 2;
      rb[0]  = fmaf(g0 * g1 * g2, xv, rb[0]);
      rb[2]  = fmaf(f0 * g1 * g2, xv, rb[2]);
      rb[10] = fmaf(g0 * f1 * g2, xv, rb[10]);
      rb[12] = fmaf(f0 * f1 * g2, xv, rb[12]);
      rb[50] = fmaf(g0 * g1 * f2, xv, rb[50]);
      rb[52] = fmaf(f0 * g1 * f2, xv, rb[52]);
      rb[60] = fmaf(g0 * f1 * f2, xv, rb[60]);
      rb[62] = fmaf(f0 * f1 * f2, xv, rb[62]);
    }
  }
  __syncthreads();
  for (int it = 0; it < 32; it++) {
    int sub = tid >> 6;
    int c4 = tid & 63;
    int nn = n0 + it * 2 + sub;
    if (nn >= N) continue;
    float4 v = make_float4(0.0f, 0.0f, 0.0f, 0.0f);
    if (c4 < 63) v = *(const float4*)&rows[(it * 2 + sub) * 254 + c4 * 4];
    ((float4*)&A[(size_t)nn * 256])[c4] = v;
  }
}

// ---------------- GEMM v3 ----------------
template <int BM, int COUT, int NT>
__global__ __launch_bounds__(NT) void gemm3_kernel(
    const float* __restrict__ A, const float* __restrict__ W,
    float* __restrict__ gpart, int M, int Kdim, int KS, int ktiles) {
  const int BK = 32;
  __shared__ float At[BK][BM + 4];
  __shared__ float Wl[BK][COUT];
  const int TC = COUT / 4;
  int tid = threadIdx.x;
  int tc = tid % TC;
  int tr = tid / TC;
  int m0 = blockIdx.x * BM;
  int kbeg = blockIdx.y * ktiles * BK;
  int kend = min(KS, kbeg + ktiles * BK);
  float ar[4][4];
#pragma unroll
  for (int i = 0; i < 4; i++)
#pragma unroll
    for (int j = 0; j < 4; j++) ar[i][j] = 0.0f;

  for (int k0 = kbeg; k0 < kend; k0 += BK) {
    for (int t = tid; t < BM * (BK / 4); t += NT) {
      int c4 = t % (BK / 4), r = t / (BK / 4);
      int m = m0 + r;
      float4 v = make_float4(0.0f, 0.0f, 0.0f, 0.0f);
      if (m < M) v = *(const float4*)&A[(size_t)m * KS + k0 + c4 * 4];
      At[c4 * 4 + 0][r] = v.x; At[c4 * 4 + 1][r] = v.y;
      At[c4 * 4 + 2][r] = v.z; At[c4 * 4 + 3][r] = v.w;
    }
    int kleft = Kdim - k0;
    if (kleft >= BK) {
      for (int t = tid; t < BK * COUT / 4; t += NT)
        ((float4*)&Wl[0][0])[t] = ((const float4*)&W[(size_t)k0 * COUT])[t];
    } else {
      for (int t = tid; t < BK * COUT; t += NT) {
        int kk = t / COUT, o = t % COUT;
        Wl[kk][o] = (kk < kleft) ? W[(size_t)(k0 + kk) * COUT + o] : 0.0f;
      }
    }
    __syncthreads();
#pragma unroll
    for (int kk = 0; kk < BK; kk++) {
      float4 a = *(const float4*)&At[kk][tr * 4];
      float4 w = *(const float4*)&Wl[kk][tc * 4];
      float av[4] = {a.x, a.y, a.z, a.w};
      float wv[4] = {w.x, w.y, w.z, w.w};
#pragma unroll
      for (int i = 0; i < 4; i++)
#pragma unroll
        for (int j = 0; j < 4; j++)
          ar[i][j] = fmaf(av[i], wv[j], ar[i][j]);
    }
    __syncthreads();
  }
  float* gp = gpart + ((size_t)blockIdx.y * M) * COUT + tc * 4;
#pragma unroll
  for (int i = 0; i < 4; i++) {
    int m = m0 + tr * 4 + i;
    if (m < M)
      *(float4*)(gp + (size_t)m * COUT) =
          make_float4(ar[i][0], ar[i][1], ar[i][2], ar[i][3]);
  }
}

// ---------------- epilogue ----------------
__global__ __launch_bounds__(256) void epilogue_kernel(
    const float* __restrict__ gpart, const int* __restrict__ degI,
    const float* __restrict__ x, const float* __restrict__ R,
    const float* __restrict__ b, float* __restrict__ h,
    int N, int Cin, int coutShift, int kchunks) {
  int tid = blockIdx.x * 256 + threadIdx.x;
  int Cout = 1 << coutShift;
  if (tid >= (N << coutShift)) return;
  int n = tid >> coutShift;
  int o = tid & (Cout - 1);
  size_t stride = (size_t)N << coutShift;
  float s = 0.0f;
  for (int c = 0; c < kchunks; c++) s += gpart[(size_t)c * stride + tid];
  s /= (float)max(degI[n], 1);
  float r = b[o];
  const float* xr = &x[n * Cin];
  for (int i = 0; i < Cin; i++) r = fmaf(xr[i], R[i * Cout + o], r);
  float v = s + r;
  h[tid] = v > 0.0f ? v : expm1f(v);
}

// ---------------- pool v5c: named-float4 accumulators, h tile in LDS, n unroll 8 ----------------
#define FMA4(c, pj, h) \
  c.x = fmaf(pj, h.x, c.x); c.y = fmaf(pj, h.y, c.y); \
  c.z = fmaf(pj, h.z, c.z); c.w = fmaf(pj, h.w, c.w);

template <int COUT, int OPT>
__global__ __launch_bounds__(256) void pool5c_kernel(
    const float* __restrict__ P, const float* __restrict__ h,
    float* __restrict__ partial, int Nsrc, int Nnext, int chunk, int items) {
  extern __shared__ float hs[];
  int c = blockIdx.y;
  int n0 = c * chunk;
  int n1 = min(Nsrc, n0 + chunk);
  int len = n1 - n0;
  for (int t = threadIdx.x; t < len * (COUT / 4); t += 256)
    ((float4*)hs)[t] = ((const float4*)&h[(size_t)n0 * COUT])[t];
  __syncthreads();
  int item = blockIdx.x * 256 + threadIdx.x;
  if (item >= items) return;
  int nj4 = Nnext >> 2;
  int j0 = (item % nj4) << 2;
  int o0 = (item / nj4) * OPT;
  const float4 z = make_float4(0.0f, 0.0f, 0.0f, 0.0f);
  float4 c00 = z, c01 = z, c02 = z, c03 = z;
  float4 c10 = z, c11 = z, c12 = z, c13 = z;
  float4 c20 = z, c21 = z, c22 = z, c23 = z;
  float4 c30 = z, c31 = z, c32 = z, c33 = z;
  const float* Pb = P + j0;

#define USTEP(pv, nn)                                                    \
  {                                                                      \
    const float4* hr = (const float4*)&hs[(nn) * COUT + o0];             \
    float4 h0 = hr[0], h1 = hr[1];                                       \
    FMA4(c00, pv.x, h0) FMA4(c01, pv.x, h1)                              \
    FMA4(c10, pv.y, h0) FMA4(c11, pv.y, h1)                              \
    FMA4(c20, pv.z, h0) FMA4(c21, pv.z, h1)                              \
    FMA4(c30, pv.w, h0) FMA4(c31, pv.w, h1)                              \
    if constexpr (OPT == 16) {                                           \
      float4 h2 = hr[2], h3 = hr[3];                                     \
      FMA4(c02, pv.x, h2) FMA4(c03, pv.x, h3)                            \
      FMA4(c12, pv.y, h2) FMA4(c13, pv.y, h3)                            \
      FMA4(c22, pv.z, h2) FMA4(c23, pv.z, h3)                            \
      FMA4(c32, pv.w, h2) FMA4(c33, pv.w, h3)                            \
    }                                                                    \
  }

  int n = 0;
  for (; n + 8 <= len; n += 8) {
    float4 pv0 = *(const float4*)&Pb[(size_t)(n0 + n + 0) * Nnext];
    float4 pv1 = *(const float4*)&Pb[(size_t)(n0 + n + 1) * Nnext];
    float4 pv2 = *(const float4*)&Pb[(size_t)(n0 + n + 2) * Nnext];
    float4 pv3 = *(const float4*)&Pb[(size_t)(n0 + n + 3) * Nnext];
    float4 pv4 = *(const float4*)&Pb[(size_t)(n0 + n + 4) * Nnext];
    float4 pv5 = *(const float4*)&Pb[(size_t)(n0 + n + 5) * Nnext];
    float4 pv6 = *(const float4*)&Pb[(size_t)(n0 + n + 6) * Nnext];
    float4 pv7 = *(const float4*)&Pb[(size_t)(n0 + n + 7) * Nnext];
    USTEP(pv0, n + 0)
    USTEP(pv1, n + 1)
    USTEP(pv2, n + 2)
    USTEP(pv3, n + 3)
    USTEP(pv4, n + 4)
    USTEP(pv5, n + 5)
    USTEP(pv6, n + 6)
    USTEP(pv7, n + 7)
  }
  for (; n < len; n++) {
    float4 pv = *(const float4*)&Pb[(size_t)(n0 + n) * Nnext];
    USTEP(pv, n)
  }
#undef USTEP

  float* pp = partial + ((size_t)c * Nnext + j0) * COUT + o0;
  *(float4*)(pp + 0 * COUT + 0) = c00;
  *(float4*)(pp + 0 * COUT + 4) = c01;
  *(float4*)(pp + 1 * COUT + 0) = c10;
  *(float4*)(pp + 1 * COUT + 4) = c11;
  *(float4*)(pp + 2 * COUT + 0) = c20;
  *(float4*)(pp + 2 * COUT + 4) = c21;
  *(float4*)(pp + 3 * COUT + 0) = c30;
  *(float4*)(pp + 3 * COUT + 4) = c31;
  if constexpr (OPT == 16) {
    *(float4*)(pp + 0 * COUT + 8)  = c02;
    *(float4*)(pp + 0 * COUT + 12) = c03;
    *(float4*)(pp + 1 * COUT + 8)  = c12;
    *(float4*)(pp + 1 * COUT + 12) = c13;
    *(float4*)(pp + 2 * COUT + 8)  = c22;
    *(float4*)(pp + 2 * COUT + 12) = c23;
    *(float4*)(pp + 3 * COUT + 8)  = c32;
    *(float4*)(pp + 3 * COUT + 12) = c33;
  }
}

// ---------------- pool reduce ----------------
__global__ __launch_bounds__(256) void preduce_kernel(
    const float* __restrict__ partial, float* __restrict__ xnext,
    int NnCout, int chunks) {
  int i = blockIdx.x * 256 + threadIdx.x;
  if (i >= NnCout) return;
  float s = 0.0f;
  for (int c = 0; c < chunks; c++) s += partial[(size_t)c * NnCout + i];
  xnext[i] = s;
}

// ---------------- final max ----------------
__global__ __launch_bounds__(128) void max_kernel(const float* __restrict__ x6,
                                                  float* __restrict__ out) {
  int o = threadIdx.x;
  float m = -3.0e38f;
  for (int n = 0; n < 16; n++) m = fmaxf(m, x6[n * 128 + o]);
  out[o] = m;
}

extern "C" void kernel_launch(void* const* d_in, const int* in_sizes, int n_in,
                              void* d_out, int out_size, void* d_ws, size_t ws_size,
                              hipStream_t stream) {
  static const int NSh[7] = {20000, 5000, 1280, 320, 80, 32, 16};
  static const int NFh[7] = {2, 16, 32, 64, 128, 128, 128};
  static const int cinSh[6]  = {1, 4, 5, 6, 7, 7};
  static const int coutSh[6] = {4, 5, 6, 7, 7, 7};
  static const int KSt[6] = {256, 2016, 4000, 8000, 16000, 16000};
  static const int kchunksTab[6] = {4, 16, 16, 32, 64, 128};
  static const int ktilesTab[6]  = {2, 4, 8, 8, 8, 4};   // kchunks*ktiles*32 >= KS
  static const int poolChunksTab[6] = {120, 80, 16, 8, 4, 2};
  static const int histOff[6] = {0, 20000, 25000, 26280, 26600, 26680};

  const float* x0 = (const float*)d_in[0];
  Ptr6i eis;
  Ptr6f eas;
  for (int l = 0; l < 6; l++) {
    eis.p[l] = (const int*)d_in[1 + 2 * l];
    eas.p[l] = (const float*)d_in[2 + 2 * l];
  }
  const float* Pm[6];
  for (int l = 0; l < 6; l++) Pm[l] = (const float*)d_in[13 + l];
  const float* Wt[6];
  const float* Rt[6];
  const float* bt[6];
  for (int l = 0; l < 6; l++) {
    Wt[l] = (const float*)d_in[19 + 3 * l];
    Rt[l] = (const float*)d_in[20 + 3 * l];
    bt[l] = (const float*)d_in[21 + 3 * l];
  }

  float* ws = (float*)d_ws;
  float* A     = ws;                       // max N*KS = 10.08M
  float* gpart = ws + 10150000;            // max 16*5000*32 = 2.56M
  float* hbuf  = ws + 12800000;            // 320000
  float* ppart = ws + 13200000;            // max 120*5000*16 = 9.6M
  float* xA    = ws + 32100000;
  float* xB    = ws + 32200000;
  int* cnt     = (int*)(ws + 32300000);    // 26712 (-> deg)
  float4* recS = (float4*)(ws + 33000000); // 26712*64 recs = 27.4MB

  // ONE-pass bucketed CSR
  hipMemsetAsync(cnt, 0, 26712 * sizeof(int), stream);
  fill_all_kernel<<<1670, 256, 0, stream>>>(eis, eas, cnt, recS);

  const float* cur = x0;
  for (int l = 0; l < 6; l++) {
    int N = NSh[l], Nn = NSh[l + 1], Cin = NFh[l], Cout = NFh[l + 1];
    int Kdim = NKER * Cin, KS = KSt[l];
    float* xnext = (l & 1) ? xB : xA;
    const int* cntL = cnt + histOff[l];
    const float4* rc = recS + (size_t)histOff[l] * CAP;

    switch (l) {
      case 0: build4_l0_kernel<<<313, 128, 0, stream>>>(cntL, rc, cur, A, N); break;
      case 1: build4_kernel<4, 8, 2000, 2016, 128><<<625, 128, 0, stream>>>(cntL, rc, cur, A); break;
      case 2: build4_kernel<5, 4, 4000, 4000, 128><<<320, 128, 0, stream>>>(cntL, rc, cur, A); break;
      case 3: build4_kernel<6, 2, 8000, 8000, 128><<<160, 128, 0, stream>>>(cntL, rc, cur, A); break;
      case 4: build4_kernel<7, 1, 16000, 16000, 128><<<80, 128, 0, stream>>>(cntL, rc, cur, A); break;
      default: build4_kernel<7, 1, 16000, 16000, 128><<<32, 128, 0, stream>>>(cntL, rc, cur, A); break;
    }

    int kchunks = kchunksTab[l], ktiles = ktilesTab[l];
    switch (l) {
      case 0: {
        dim3 g((N + 127) / 128, kchunks);
        gemm3_kernel<128, 16, 128><<<g, 128, 0, stream>>>(A, Wt[l], gpart, N, Kdim, KS, ktiles);
        break;
      }
      case 1: {
        dim3 g((N + 127) / 128, kchunks);
        gemm3_kernel<128, 32, 256><<<g, 256, 0, stream>>>(A, Wt[l], gpart, N, Kdim, KS, ktiles);
        break;
      }
      case 2: {
        dim3 g((N + 63) / 64, kchunks);
        gemm3_kernel<64, 64, 256><<<g, 256, 0, stream>>>(A, Wt[l], gpart, N, Kdim, KS, ktiles);
        break;
      }
      default: {
        dim3 g((N + 31) / 32, kchunks);
        gemm3_kernel<32, 128, 256><<<g, 256, 0, stream>>>(A, Wt[l], gpart, N, Kdim, KS, ktiles);
        break;
      }
    }

    int ethreads = N << coutSh[l];
    epilogue_kernel<<<(ethreads + 255) / 256, 256, 0, stream>>>(
        gpart, cntL, cur, Rt[l], bt[l], hbuf, N, Cin, coutSh[l], kchunks);

    int pc = poolChunksTab[l];
    int chunk = (N + pc - 1) / pc;
    size_t ldsB = (size_t)chunk * Cout * sizeof(float);
    int items, gx;
    switch (Cout) {
      case 16:
        items = (Nn >> 2) * 1;
        gx = (items + 255) / 256;
        pool5c_kernel<16, 16><<<dim3(gx, pc), 256, ldsB, stream>>>(Pm[l], hbuf, ppart, N, Nn, chunk, items);
        break;
      case 32:
        items = (Nn >> 2) * 2;
        gx = (items + 255) / 256;
        pool5c_kernel<32, 16><<<dim3(gx, pc), 256, ldsB, stream>>>(Pm[l], hbuf, ppart, N, Nn, chunk, items);
        break;
      case 64:
        items = (Nn >> 2) * 8;
        gx = (items + 255) / 256;
        pool5c_kernel<64, 8><<<dim3(gx, pc), 256, ldsB, stream>>>(Pm[l], hbuf, ppart, N, Nn, chunk, items);
        break;
      default:
        items = (Nn >> 2) * 16;
        gx = (items + 255) / 256;
        pool5c_kernel<128, 8><<<dim3(gx, pc), 256, ldsB, stream>>>(Pm[l], hbuf, ppart, N, Nn, chunk, items);
        break;
    }
    int NnCout = Nn << coutSh[l];
    preduce_kernel<<<(NnCout + 255) / 256, 256, 0, stream>>>(ppart, xnext, NnCout, pc);

    cur = xnext;
  }

  max_kernel<<<1, 128, 0, stream>>>(cur, (float*)d_out);
}